// Round 4
// baseline (637.283 us; speedup 1.0000x reference)
//
#include <hip/hip_runtime.h>
#include <cstdint>
#include <cstddef>

// ---------------- problem constants (fixed by setup_inputs) ----------------
#define L_SEQ   4096
#define NBATCH  8
#define NDIM    256
#define DIN     512
#define NSTATE  16
#define NC_CHUNKS 32
#define CLEN    (L_SEQ / NC_CHUNKS)      // 128
#define BLROWS  (NBATCH * L_SEQ)         // 32768

typedef unsigned short u16;
typedef __attribute__((ext_vector_type(8))) short short8;   // 8 x bf16
typedef __attribute__((ext_vector_type(4))) float f32x4;

#define LOG2E 1.44269504088896340736f

__device__ __forceinline__ u16 f2bf(float f) {
  unsigned u = __float_as_uint(f);
  return (u16)((u + 0x7FFFu + ((u >> 16) & 1u)) >> 16);   // RNE
}
__device__ __forceinline__ float bf2f(u16 v) {
  return __uint_as_float(((unsigned)v) << 16);
}
__device__ __forceinline__ float exp2fast(float x) {
#if __has_builtin(__builtin_amdgcn_exp2f)
  return __builtin_amdgcn_exp2f(x);
#else
  return exp2f(x);
#endif
}
__device__ __forceinline__ float sigmoid_(float x) {
  return 1.0f / (1.0f + exp2fast(-x * LOG2E));
}
__device__ __forceinline__ float silu_(float x) { return x * sigmoid_(x); }
__device__ __forceinline__ float softplus_(float x) {
  return (x > 15.f) ? x : __logf(1.0f + exp2fast(x * LOG2E));
}

// ---------------- prep: weight bf16 conversion + A2 = -exp(A_log)*log2e ----
__global__ __launch_bounds__(256) void k_prep(
    const float* __restrict__ in_w, const float* __restrict__ xp_f,
    const float* __restrict__ xp_b, const float* __restrict__ out_w,
    const float* __restrict__ Alog_f, const float* __restrict__ Alog_b,
    u16* __restrict__ wb_in, u16* __restrict__ wb_xp, u16* __restrict__ wb_cat,
    float* __restrict__ a2) {
  int i = blockIdx.x * 256 + threadIdx.x;
  if (i < 1024 * 256) wb_in[i] = f2bf(in_w[i]);
  if (i < 2 * 48 * 512) {
    int d = i / (48 * 512), r = i % (48 * 512);
    wb_xp[i] = f2bf((d ? xp_b : xp_f)[r]);
  }
  if (i < 256 * 1024) {
    int c = i >> 10, k = i & 1023;
    wb_cat[i] = f2bf(out_w[c * 512 + (k & 511)]);    // [W | W] duplicated
  }
  if (i < 2 * 8192) {
    int d = i >> 13, r = i & 8191;
    a2[i] = -__expf((d ? Alog_b : Alog_f)[r]) * LOG2E;
  }
}

// ---------------- LayerNorm + transpose: x(B,C,L) -> xn_bf(B*L, C) ---------
__global__ __launch_bounds__(256) void k_ln(
    const float* __restrict__ x, const float* __restrict__ w,
    const float* __restrict__ bb, u16* __restrict__ xn) {
  __shared__ float tile[256][65];
  __shared__ float red[2][4][64];
  __shared__ float mu_s[64], rs_s[64];
  int b = blockIdx.y, l0 = blockIdx.x * 64;
  int t = threadIdx.x, lane = t & 63, r = t >> 6;
  const float* xb = x + (size_t)b * 256 * L_SEQ;
  for (int cc = 0; cc < 64; ++cc) {
    int c = cc * 4 + r;
    tile[c][lane] = xb[(size_t)c * L_SEQ + l0 + lane];
  }
  __syncthreads();
  float s = 0.f, sq = 0.f;
  for (int c = r * 64; c < r * 64 + 64; ++c) {
    float v = tile[c][lane];
    s += v; sq += v * v;
  }
  red[0][r][lane] = s; red[1][r][lane] = sq;
  __syncthreads();
  if (t < 64) {
    float S = red[0][0][t] + red[0][1][t] + red[0][2][t] + red[0][3][t];
    float Q = red[1][0][t] + red[1][1][t] + red[1][2][t] + red[1][3][t];
    float mu = S * (1.f / 256.f);
    float var = Q * (1.f / 256.f) - mu * mu;
    mu_s[t] = mu;
    rs_s[t] = rsqrtf(var + 1e-5f);
  }
  __syncthreads();
  float wc = w[t], bc = bb[t];
  for (int l = 0; l < 64; ++l) {
    float v = (tile[t][l] - mu_s[l]) * rs_s[l] * wc + bc;
    xn[((size_t)b * L_SEQ + l0 + l) * 256 + t] = f2bf(v);
  }
}

// ---------------- GEMM1: xz = xn @ in_proj_w^T  (M=32768,N=1024,K=256) -----
// split cols: [0,512) -> xbuf bf16, [512,1024) -> zbuf bf16
__global__ __launch_bounds__(256) void k_gemm_in(
    const u16* __restrict__ A, const u16* __restrict__ Bm,
    u16* __restrict__ xout, u16* __restrict__ zout) {
  __shared__ u16 lA[128 * 32], lB[128 * 32];
  int mt = blockIdx.x, nt = blockIdx.y;
  int t = threadIdx.x, lane = t & 63, wid = t >> 6;
  int wr = wid >> 1, wc = wid & 1;
  f32x4 acc[4][4] = {};
  const u16* Ab = A + (size_t)mt * 128 * 256;
  const u16* Bb = Bm + (size_t)nt * 128 * 256;
  for (int kt = 0; kt < 8; ++kt) {
    int k0 = kt * 32;
    __syncthreads();
#pragma unroll
    for (int i = 0; i < 2; ++i) {
      int lin = i * 256 + t, row = lin >> 2, kc = lin & 3;
      *(short8*)&lA[lin * 8] = *(const short8*)&Ab[row * 256 + k0 + kc * 8];
      *(short8*)&lB[lin * 8] = *(const short8*)&Bb[row * 256 + k0 + kc * 8];
    }
    __syncthreads();
    short8 av[4], bv[4];
#pragma unroll
    for (int i = 0; i < 4; ++i)
      av[i] = *(const short8*)&lA[(wr * 64 + i * 16 + (lane & 15)) * 32 + (lane >> 4) * 8];
#pragma unroll
    for (int j = 0; j < 4; ++j)
      bv[j] = *(const short8*)&lB[(wc * 64 + j * 16 + (lane & 15)) * 32 + (lane >> 4) * 8];
#pragma unroll
    for (int i = 0; i < 4; ++i)
#pragma unroll
      for (int j = 0; j < 4; ++j)
        acc[i][j] = __builtin_amdgcn_mfma_f32_16x16x32_bf16(av[i], bv[j], acc[i][j], 0, 0, 0);
  }
  int colbase = nt * 128 + wc * 64;
  u16* dst = (colbase < 512) ? xout : zout;
  int cadj = (colbase < 512) ? colbase : colbase - 512;
  size_t rowbase = (size_t)mt * 128 + wr * 64;
#pragma unroll
  for (int i = 0; i < 4; ++i)
#pragma unroll
    for (int j = 0; j < 4; ++j) {
      int c = cadj + j * 16 + (lane & 15);
      size_t rr = rowbase + i * 16 + ((lane >> 4) << 2);
#pragma unroll
      for (int ii = 0; ii < 4; ++ii)
        dst[(rr + ii) * 512 + c] = f2bf(acc[i][j][ii]);
    }
}

// ---------------- conv(d,k=4,causal)+SiLU -> bf16 (logical order per dir) --
__global__ __launch_bounds__(512) void k_conv(
    const u16* __restrict__ xbuf,
    const float* __restrict__ cw_f, const float* __restrict__ cb_f,
    const float* __restrict__ cw_b, const float* __restrict__ cb_b,
    u16* __restrict__ xconv_bf) {
  int d = threadIdx.x;
  int b = blockIdx.y, dir = blockIdx.z;
  int t0 = blockIdx.x * 64;
  const float* cw = (dir ? cw_b : cw_f) + d * 4;
  float w0 = cw[0], w1 = cw[1], w2 = cw[2], w3 = cw[3];
  float bias = (dir ? cb_b : cb_f)[d];
  const u16* xb = xbuf + (size_t)b * L_SEQ * 512 + d;
  u16* ob = xconv_bf + ((size_t)dir * BLROWS + (size_t)b * L_SEQ) * 512 + d;
  float tp0 = 0.f, tp1 = 0.f, tp2 = 0.f;
  if (t0 >= 1) tp2 = bf2f(xb[(size_t)(dir ? (L_SEQ - t0) : (t0 - 1)) * 512]);
  if (t0 >= 2) tp1 = bf2f(xb[(size_t)(dir ? (L_SEQ + 1 - t0) : (t0 - 2)) * 512]);
  if (t0 >= 3) tp0 = bf2f(xb[(size_t)(dir ? (L_SEQ + 2 - t0) : (t0 - 3)) * 512]);
#pragma unroll 4
  for (int tt = t0; tt < t0 + 64; ++tt) {
    int px = dir ? (L_SEQ - 1 - tt) : tt;
    float xin = bf2f(xb[(size_t)px * 512]);
    float u = bias + w0 * tp0 + w1 * tp1 + w2 * tp2 + w3 * xin;
    ob[(size_t)tt * 512] = f2bf(silu_(u));
    tp0 = tp1; tp1 = tp2; tp2 = xin;
  }
}

// ---------------- GEMM2: dbl = xconv @ x_proj_w^T (M=32768,N=48,K=512) -----
__global__ __launch_bounds__(256) void k_gemm_xp(
    const u16* __restrict__ xc, const u16* __restrict__ wxp,
    float* __restrict__ dbl) {
  __shared__ u16 lA[128 * 32], lB[48 * 32];
  int mt = blockIdx.x, dir = blockIdx.y;
  int t = threadIdx.x, lane = t & 63, wid = t >> 6;
  const u16* Ab = xc + ((size_t)dir * BLROWS + (size_t)mt * 128) * 512;
  const u16* Bb = wxp + (size_t)dir * 48 * 512;
  float* Ob = dbl + ((size_t)dir * BLROWS + (size_t)mt * 128) * 48;
  f32x4 acc[2][3] = {};
  for (int kt = 0; kt < 16; ++kt) {
    int k0 = kt * 32;
    __syncthreads();
#pragma unroll
    for (int i = 0; i < 2; ++i) {
      int lin = i * 256 + t, row = lin >> 2, kc = lin & 3;
      *(short8*)&lA[lin * 8] = *(const short8*)&Ab[row * 512 + k0 + kc * 8];
    }
    if (t < 192) {
      int row = t >> 2, kc = t & 3;
      *(short8*)&lB[t * 8] = *(const short8*)&Bb[row * 512 + k0 + kc * 8];
    }
    __syncthreads();
    short8 av[2], bv[3];
#pragma unroll
    for (int i = 0; i < 2; ++i)
      av[i] = *(const short8*)&lA[(wid * 32 + i * 16 + (lane & 15)) * 32 + (lane >> 4) * 8];
#pragma unroll
    for (int j = 0; j < 3; ++j)
      bv[j] = *(const short8*)&lB[(j * 16 + (lane & 15)) * 32 + (lane >> 4) * 8];
#pragma unroll
    for (int i = 0; i < 2; ++i)
#pragma unroll
      for (int j = 0; j < 3; ++j)
        acc[i][j] = __builtin_amdgcn_mfma_f32_16x16x32_bf16(av[i], bv[j], acc[i][j], 0, 0, 0);
  }
#pragma unroll
  for (int i = 0; i < 2; ++i)
#pragma unroll
    for (int j = 0; j < 3; ++j) {
      int c = j * 16 + (lane & 15);
      int rr = wid * 32 + i * 16 + ((lane >> 4) << 2);
#pragma unroll
      for (int ii = 0; ii < 4; ++ii)
        Ob[(size_t)(rr + ii) * 48 + c] = acc[i][j][ii];
    }
}

// ---------------- scan phase A: per-chunk aggregates (P, Hf) ---------------
// lane = channel d; conv + dt_proj + softplus recomputed inline
__global__ __launch_bounds__(512) void k_scanA(
    const u16* __restrict__ xbuf, const float* __restrict__ dbl,
    const float* __restrict__ a2buf,
    const float* __restrict__ cw_f, const float* __restrict__ cb_f,
    const float* __restrict__ cw_b, const float* __restrict__ cb_b,
    const float* __restrict__ dtw_f, const float* __restrict__ dtb_f,
    const float* __restrict__ dtw_b, const float* __restrict__ dtb_b,
    float* __restrict__ Pb, float* __restrict__ Hf) {
  int chunk = blockIdx.x, b = blockIdx.y, dir = blockIdx.z;
  int d = threadIdx.x;
  alignas(16) float a2r[16], w3r[16];
  const float* A2 = a2buf + dir * 8192 + d * 16;
  const float* dtw = (dir ? dtw_b : dtw_f) + d * 16;
#pragma unroll
  for (int q = 0; q < 4; ++q) {
    *(float4*)&a2r[q * 4] = *(const float4*)&A2[q * 4];
    *(float4*)&w3r[q * 4] = *(const float4*)&dtw[q * 4];
  }
  const float* cw = (dir ? cw_b : cw_f) + d * 4;
  float w0 = cw[0], w1 = cw[1], w2 = cw[2], w3 = cw[3];
  float cbias = (dir ? cb_b : cb_f)[d];
  float dtbias = (dir ? dtb_b : dtb_f)[d];
  const u16* xb = xbuf + (size_t)b * L_SEQ * 512 + d;
  const float* dbr = dbl + ((size_t)dir * BLROWS + (size_t)b * L_SEQ) * 48;
  int t0 = chunk * CLEN;
  float tp0 = 0.f, tp1 = 0.f, tp2 = 0.f;
  if (t0 >= 1) tp2 = bf2f(xb[(size_t)(dir ? (L_SEQ - t0) : (t0 - 1)) * 512]);
  if (t0 >= 2) tp1 = bf2f(xb[(size_t)(dir ? (L_SEQ + 1 - t0) : (t0 - 2)) * 512]);
  if (t0 >= 3) tp0 = bf2f(xb[(size_t)(dir ? (L_SEQ + 2 - t0) : (t0 - 3)) * 512]);
  float h[16];
#pragma unroll
  for (int n = 0; n < 16; ++n) h[n] = 0.f;
  float S = 0.f;
  for (int tt = t0; tt < t0 + CLEN; ++tt) {
    int px = dir ? (L_SEQ - 1 - tt) : tt;
    float xin = bf2f(xb[(size_t)px * 512]);
    float u = silu_(cbias + w0 * tp0 + w1 * tp1 + w2 * tp2 + w3 * xin);
    tp0 = tp1; tp1 = tp2; tp2 = xin;
    const float* row = dbr + (size_t)tt * 48;
    float v0 = 0.f, v1 = 0.f, v2 = 0.f, v3 = 0.f;
#pragma unroll
    for (int q = 0; q < 4; ++q) {
      float4 dq = *(const float4*)&row[q * 4];
      v0 += dq.x * w3r[4 * q];     v1 += dq.y * w3r[4 * q + 1];
      v2 += dq.z * w3r[4 * q + 2]; v3 += dq.w * w3r[4 * q + 3];
    }
    float delta = softplus_(dtbias + ((v0 + v1) + (v2 + v3)));
    S += delta;
    float du = delta * u;
    alignas(16) float Bv[16];
#pragma unroll
    for (int q = 0; q < 4; ++q) *(float4*)&Bv[q * 4] = *(const float4*)&row[16 + q * 4];
#pragma unroll
    for (int n = 0; n < 16; ++n) {
      float e = exp2fast(delta * a2r[n]);
      h[n] = fmaf(e, h[n], du * Bv[n]);
    }
  }
  size_t base = (((size_t)dir * NBATCH + b) * NC_CHUNKS + chunk) * 8192 + (size_t)d * 16;
#pragma unroll
  for (int n = 0; n < 16; ++n) {
    Hf[base + n] = h[n];
    Pb[base + n] = exp2fast(S * a2r[n]);
  }
}

// ---------------- scan phase B: compose chunk aggregates -> Hinit ----------
__global__ __launch_bounds__(512) void k_scanB(
    const float* __restrict__ P, const float* __restrict__ Hf,
    float* __restrict__ Hi) {
  int dir = blockIdx.z, b = blockIdx.y;
  int j = blockIdx.x * 512 + threadIdx.x;   // 0..8191
  size_t base0 = (((size_t)dir * NBATCH + b) * NC_CHUNKS) * 8192 + j;
  float h = 0.f;
  for (int c = 0; c < NC_CHUNKS; ++c) {
    size_t idx = base0 + (size_t)c * 8192;
    Hi[idx] = h;
    h = P[idx] * h + Hf[idx];
  }
}

// ---------------- scan phase C: full scan + D*u + silu(z) gate -> ycat -----
__global__ __launch_bounds__(512) void k_scanC(
    const u16* __restrict__ xbuf, const u16* __restrict__ zbuf,
    const float* __restrict__ dbl, const float* __restrict__ a2buf,
    const float* __restrict__ cw_f, const float* __restrict__ cb_f,
    const float* __restrict__ cw_b, const float* __restrict__ cb_b,
    const float* __restrict__ dtw_f, const float* __restrict__ dtb_f,
    const float* __restrict__ dtw_b, const float* __restrict__ dtb_b,
    const float* __restrict__ D_f, const float* __restrict__ D_b,
    const float* __restrict__ Hi, u16* __restrict__ ycat) {
  int chunk = blockIdx.x, b = blockIdx.y, dir = blockIdx.z;
  int d = threadIdx.x;
  alignas(16) float a2r[16], w3r[16];
  const float* A2 = a2buf + dir * 8192 + d * 16;
  const float* dtw = (dir ? dtw_b : dtw_f) + d * 16;
#pragma unroll
  for (int q = 0; q < 4; ++q) {
    *(float4*)&a2r[q * 4] = *(const float4*)&A2[q * 4];
    *(float4*)&w3r[q * 4] = *(const float4*)&dtw[q * 4];
  }
  const float* cw = (dir ? cw_b : cw_f) + d * 4;
  float w0 = cw[0], w1 = cw[1], w2 = cw[2], w3 = cw[3];
  float cbias = (dir ? cb_b : cb_f)[d];
  float dtbias = (dir ? dtb_b : dtb_f)[d];
  float Dd = (dir ? D_b : D_f)[d];
  const u16* xb = xbuf + (size_t)b * L_SEQ * 512 + d;
  const u16* zb = zbuf + (size_t)b * L_SEQ * 512 + d;
  const float* dbr = dbl + ((size_t)dir * BLROWS + (size_t)b * L_SEQ) * 48;
  u16* yb = ycat + (size_t)b * L_SEQ * 1024 + dir * 512 + d;
  int t0 = chunk * CLEN;
  float tp0 = 0.f, tp1 = 0.f, tp2 = 0.f;
  if (t0 >= 1) tp2 = bf2f(xb[(size_t)(dir ? (L_SEQ - t0) : (t0 - 1)) * 512]);
  if (t0 >= 2) tp1 = bf2f(xb[(size_t)(dir ? (L_SEQ + 1 - t0) : (t0 - 2)) * 512]);
  if (t0 >= 3) tp0 = bf2f(xb[(size_t)(dir ? (L_SEQ + 2 - t0) : (t0 - 3)) * 512]);
  alignas(16) float h[16];
  size_t hbase = (((size_t)dir * NBATCH + b) * NC_CHUNKS + chunk) * 8192 + (size_t)d * 16;
#pragma unroll
  for (int q = 0; q < 4; ++q) *(float4*)&h[q * 4] = *(const float4*)&Hi[hbase + q * 4];
  for (int tt = t0; tt < t0 + CLEN; ++tt) {
    int px = dir ? (L_SEQ - 1 - tt) : tt;
    float xin = bf2f(xb[(size_t)px * 512]);
    float u = silu_(cbias + w0 * tp0 + w1 * tp1 + w2 * tp2 + w3 * xin);
    tp0 = tp1; tp1 = tp2; tp2 = xin;
    const float* row = dbr + (size_t)tt * 48;
    float v0 = 0.f, v1 = 0.f, v2 = 0.f, v3 = 0.f;
#pragma unroll
    for (int q = 0; q < 4; ++q) {
      float4 dq = *(const float4*)&row[q * 4];
      v0 += dq.x * w3r[4 * q];     v1 += dq.y * w3r[4 * q + 1];
      v2 += dq.z * w3r[4 * q + 2]; v3 += dq.w * w3r[4 * q + 3];
    }
    float delta = softplus_(dtbias + ((v0 + v1) + (v2 + v3)));
    float du = delta * u;
    alignas(16) float Bv[16], Cv[16];
#pragma unroll
    for (int q = 0; q < 4; ++q) {
      *(float4*)&Bv[q * 4] = *(const float4*)&row[16 + q * 4];
      *(float4*)&Cv[q * 4] = *(const float4*)&row[32 + q * 4];
    }
    float y0 = 0.f, y1 = 0.f, y2 = 0.f, y3 = 0.f;
#pragma unroll
    for (int n = 0; n < 16; n += 4) {
      float e0 = exp2fast(delta * a2r[n]);
      float e1 = exp2fast(delta * a2r[n + 1]);
      float e2 = exp2fast(delta * a2r[n + 2]);
      float e3 = exp2fast(delta * a2r[n + 3]);
      h[n]     = fmaf(e0, h[n],     du * Bv[n]);
      h[n + 1] = fmaf(e1, h[n + 1], du * Bv[n + 1]);
      h[n + 2] = fmaf(e2, h[n + 2], du * Bv[n + 2]);
      h[n + 3] = fmaf(e3, h[n + 3], du * Bv[n + 3]);
      y0 = fmaf(h[n], Cv[n], y0);
      y1 = fmaf(h[n + 1], Cv[n + 1], y1);
      y2 = fmaf(h[n + 2], Cv[n + 2], y2);
      y3 = fmaf(h[n + 3], Cv[n + 3], y3);
    }
    float y = ((y0 + y1) + (y2 + y3)) + u * Dd;
    float z = bf2f(zb[(size_t)px * 512]);
    yb[(size_t)px * 1024] = f2bf(y * silu_(z));
  }
}

// ---------------- GEMM3: out = ycat @ [W|W]^T (M=32768,N=256,K=1024) -------
// epilogue writes transposed: out[b][c][l]
__global__ __launch_bounds__(256) void k_gemm_out(
    const u16* __restrict__ A, const u16* __restrict__ Bm,
    float* __restrict__ out) {
  __shared__ u16 lA[128 * 32], lB[128 * 32];
  int mt = blockIdx.x, nt = blockIdx.y;
  int t = threadIdx.x, lane = t & 63, wid = t >> 6;
  int wr = wid >> 1, wc = wid & 1;
  f32x4 acc[4][4] = {};
  const u16* Ab = A + (size_t)mt * 128 * 1024;
  const u16* Bb = Bm + (size_t)nt * 128 * 1024;
  for (int kt = 0; kt < 32; ++kt) {
    int k0 = kt * 32;
    __syncthreads();
#pragma unroll
    for (int i = 0; i < 2; ++i) {
      int lin = i * 256 + t, row = lin >> 2, kc = lin & 3;
      *(short8*)&lA[lin * 8] = *(const short8*)&Ab[(size_t)row * 1024 + k0 + kc * 8];
      *(short8*)&lB[lin * 8] = *(const short8*)&Bb[(size_t)row * 1024 + k0 + kc * 8];
    }
    __syncthreads();
    short8 av[4], bv[4];
#pragma unroll
    for (int i = 0; i < 4; ++i)
      av[i] = *(const short8*)&lA[(wr * 64 + i * 16 + (lane & 15)) * 32 + (lane >> 4) * 8];
#pragma unroll
    for (int j = 0; j < 4; ++j)
      bv[j] = *(const short8*)&lB[(wc * 64 + j * 16 + (lane & 15)) * 32 + (lane >> 4) * 8];
#pragma unroll
    for (int i = 0; i < 4; ++i)
#pragma unroll
      for (int j = 0; j < 4; ++j)
        acc[i][j] = __builtin_amdgcn_mfma_f32_16x16x32_bf16(av[i], bv[j], acc[i][j], 0, 0, 0);
  }
#pragma unroll
  for (int i = 0; i < 4; ++i)
#pragma unroll
    for (int j = 0; j < 4; ++j) {
      int c = nt * 128 + wc * 64 + j * 16 + (lane & 15);
      int r0 = mt * 128 + wr * 64 + i * 16 + ((lane >> 4) << 2);
      int b = r0 >> 12, l0 = r0 & 4095;
      float4 val;
      val.x = acc[i][j][0]; val.y = acc[i][j][1];
      val.z = acc[i][j][2]; val.w = acc[i][j][3];
      *(float4*)&out[((size_t)b * 256 + c) * 4096 + l0] = val;
    }
}

// ---------------- host launcher --------------------------------------------
extern "C" void kernel_launch(void* const* d_in, const int* in_sizes, int n_in,
                              void* d_out, int out_size, void* d_ws, size_t ws_size,
                              hipStream_t stream) {
  (void)in_sizes; (void)n_in; (void)out_size; (void)ws_size;
  const float* x      = (const float*)d_in[0];
  const float* ln_w   = (const float*)d_in[1];
  const float* ln_b   = (const float*)d_in[2];
  const float* in_w   = (const float*)d_in[3];
  const float* cw_f   = (const float*)d_in[4];
  const float* cb_f   = (const float*)d_in[5];
  const float* xp_f   = (const float*)d_in[6];
  const float* dtw_f  = (const float*)d_in[7];
  const float* dtb_f  = (const float*)d_in[8];
  const float* Alog_f = (const float*)d_in[9];
  const float* D_f    = (const float*)d_in[10];
  const float* cw_b   = (const float*)d_in[11];
  const float* cb_b   = (const float*)d_in[12];
  const float* xp_b   = (const float*)d_in[13];
  const float* dtw_b  = (const float*)d_in[14];
  const float* dtb_b  = (const float*)d_in[15];
  const float* Alog_b = (const float*)d_in[16];
  const float* D_b    = (const float*)d_in[17];
  const float* out_w  = (const float*)d_in[18];

  char* ws = (char*)d_ws;
  size_t off = 0;
  auto alloc = [&](size_t bytes) -> void* {
    void* p = ws + off;
    off += (bytes + 255) & ~(size_t)255;
    return p;
  };
  // Lifetime-aliased workspace layout (peak ~198 MB):
  //  xn_bf [k_ln -> k_gemm_in]  aliases  Pbuf [k_scanA -> k_scanB]  (both 16.78 MB)
  //  xconv [k_conv -> k_gemm_xp] aliases ycat [k_scanC -> k_gemm_out] (both 67 MB)
  u16*   xn_bf  = (u16*)  alloc((size_t)BLROWS * 256 * 2);        // 16.78 MB (== Pbuf)
  u16*   wb_in  = (u16*)  alloc((size_t)1024 * 256 * 2);
  u16*   wb_xp  = (u16*)  alloc((size_t)2 * 48 * 512 * 2);
  u16*   wb_cat = (u16*)  alloc((size_t)256 * 1024 * 2);
  float* a2buf  = (float*)alloc((size_t)2 * 8192 * 4);
  u16*   xbuf   = (u16*)  alloc((size_t)BLROWS * 512 * 2);        // 33.5 MB bf16
  u16*   zbuf   = (u16*)  alloc((size_t)BLROWS * 512 * 2);        // 33.5 MB bf16
  u16*   xconv  = (u16*)  alloc((size_t)2 * BLROWS * 512 * 2);    // 67 MB (== ycat)
  float* dblb   = (float*)alloc((size_t)2 * BLROWS * 48 * 4);     // 12.6 MB
  float* Hfbuf  = (float*)alloc((size_t)2 * NBATCH * NC_CHUNKS * 8192 * 4);  // 16.78 MB
  float* Hibuf  = (float*)alloc((size_t)2 * NBATCH * NC_CHUNKS * 8192 * 4);  // 16.78 MB
  float* Pbuf   = (float*)xn_bf;   // alias: xn_bf dead after k_gemm_in
  u16*   ycat   = xconv;           // alias: xconv dead after k_gemm_xp

  hipLaunchKernelGGL(k_prep, dim3(1024), dim3(256), 0, stream,
                     in_w, xp_f, xp_b, out_w, Alog_f, Alog_b,
                     wb_in, wb_xp, wb_cat, a2buf);
  hipLaunchKernelGGL(k_ln, dim3(L_SEQ / 64, NBATCH), dim3(256), 0, stream,
                     x, ln_w, ln_b, xn_bf);
  hipLaunchKernelGGL(k_gemm_in, dim3(BLROWS / 128, 8), dim3(256), 0, stream,
                     xn_bf, wb_in, xbuf, zbuf);
  hipLaunchKernelGGL(k_conv, dim3(L_SEQ / 64, NBATCH, 2), dim3(512), 0, stream,
                     xbuf, cw_f, cb_f, cw_b, cb_b, xconv);
  hipLaunchKernelGGL(k_gemm_xp, dim3(BLROWS / 128, 2), dim3(256), 0, stream,
                     xconv, wb_xp, dblb);
  hipLaunchKernelGGL(k_scanA, dim3(NC_CHUNKS, NBATCH, 2), dim3(512), 0, stream,
                     xbuf, dblb, a2buf, cw_f, cb_f, cw_b, cb_b,
                     dtw_f, dtb_f, dtw_b, dtb_b, Pbuf, Hfbuf);
  hipLaunchKernelGGL(k_scanB, dim3(16, NBATCH, 2), dim3(512), 0, stream,
                     Pbuf, Hfbuf, Hibuf);
  hipLaunchKernelGGL(k_scanC, dim3(NC_CHUNKS, NBATCH, 2), dim3(512), 0, stream,
                     xbuf, zbuf, dblb, a2buf, cw_f, cb_f, cw_b, cb_b,
                     dtw_f, dtb_f, dtw_b, dtb_b, D_f, D_b, Hibuf, ycat);
  hipLaunchKernelGGL(k_gemm_out, dim3(BLROWS / 128, 2), dim3(256), 0, stream,
                     ycat, wb_cat, (float*)d_out);
}

// Round 6
// 621.097 us; speedup vs baseline: 1.0261x; 1.0261x over previous
//
#include <hip/hip_runtime.h>
#include <cstdint>
#include <cstddef>

// ---------------- problem constants (fixed by setup_inputs) ----------------
#define L_SEQ   4096
#define NBATCH  8
#define NDIM    256
#define DIN     512
#define NSTATE  16
#define NC_CHUNKS 32
#define CLEN    (L_SEQ / NC_CHUNKS)      // 128
#define BLROWS  (NBATCH * L_SEQ)         // 32768

typedef unsigned short u16;
typedef __attribute__((ext_vector_type(8))) short short8;   // 8 x bf16
typedef __attribute__((ext_vector_type(4))) float f32x4;

#define LOG2E 1.44269504088896340736f

__device__ __forceinline__ u16 f2bf(float f) {
  unsigned u = __float_as_uint(f);
  return (u16)((u + 0x7FFFu + ((u >> 16) & 1u)) >> 16);   // RNE
}
__device__ __forceinline__ float bf2f(u16 v) {
  return __uint_as_float(((unsigned)v) << 16);
}
__device__ __forceinline__ float exp2fast(float x) {
#if __has_builtin(__builtin_amdgcn_exp2f)
  return __builtin_amdgcn_exp2f(x);
#else
  return exp2f(x);
#endif
}
__device__ __forceinline__ float sigmoid_(float x) {
  return 1.0f / (1.0f + exp2fast(-x * LOG2E));
}
__device__ __forceinline__ float silu_(float x) { return x * sigmoid_(x); }
__device__ __forceinline__ float softplus_(float x) {
  return (x > 15.f) ? x : __logf(1.0f + exp2fast(x * LOG2E));
}

// ---------------- prep: weight bf16 conversion + A2 = -exp(A_log)*log2e ----
__global__ __launch_bounds__(256) void k_prep(
    const float* __restrict__ in_w, const float* __restrict__ xp_f,
    const float* __restrict__ xp_b, const float* __restrict__ out_w,
    const float* __restrict__ Alog_f, const float* __restrict__ Alog_b,
    u16* __restrict__ wb_in, u16* __restrict__ wb_xp, u16* __restrict__ wb_cat,
    float* __restrict__ a2) {
  int i = blockIdx.x * 256 + threadIdx.x;
  if (i < 1024 * 256) wb_in[i] = f2bf(in_w[i]);
  if (i < 2 * 48 * 512) {
    int d = i / (48 * 512), r = i % (48 * 512);
    wb_xp[i] = f2bf((d ? xp_b : xp_f)[r]);
  }
  if (i < 256 * 1024) {
    int c = i >> 10, k = i & 1023;
    wb_cat[i] = f2bf(out_w[c * 512 + (k & 511)]);    // [W | W] duplicated
  }
  if (i < 2 * 8192) {
    int d = i >> 13, r = i & 8191;
    a2[i] = -__expf((d ? Alog_b : Alog_f)[r]) * LOG2E;
  }
}

// ---------------- LayerNorm + transpose: x(B,C,L) -> xn_bf(B*L, C) ---------
__global__ __launch_bounds__(256) void k_ln(
    const float* __restrict__ x, const float* __restrict__ w,
    const float* __restrict__ bb, u16* __restrict__ xn) {
  __shared__ float tile[256][65];
  __shared__ float red[2][4][64];
  __shared__ float mu_s[64], rs_s[64];
  int b = blockIdx.y, l0 = blockIdx.x * 64;
  int t = threadIdx.x, lane = t & 63, r = t >> 6;
  const float* xb = x + (size_t)b * 256 * L_SEQ;
  for (int cc = 0; cc < 64; ++cc) {
    int c = cc * 4 + r;
    tile[c][lane] = xb[(size_t)c * L_SEQ + l0 + lane];
  }
  __syncthreads();
  float s = 0.f, sq = 0.f;
  for (int c = r * 64; c < r * 64 + 64; ++c) {
    float v = tile[c][lane];
    s += v; sq += v * v;
  }
  red[0][r][lane] = s; red[1][r][lane] = sq;
  __syncthreads();
  if (t < 64) {
    float S = red[0][0][t] + red[0][1][t] + red[0][2][t] + red[0][3][t];
    float Q = red[1][0][t] + red[1][1][t] + red[1][2][t] + red[1][3][t];
    float mu = S * (1.f / 256.f);
    float var = Q * (1.f / 256.f) - mu * mu;
    mu_s[t] = mu;
    rs_s[t] = rsqrtf(var + 1e-5f);
  }
  __syncthreads();
  float wc = w[t], bc = bb[t];
  for (int l = 0; l < 64; ++l) {
    float v = (tile[t][l] - mu_s[l]) * rs_s[l] * wc + bc;
    xn[((size_t)b * L_SEQ + l0 + l) * 256 + t] = f2bf(v);
  }
}

// ---------------- GEMM1: xz = xn @ in_proj_w^T  (M=32768,N=1024,K=256) -----
// split cols: [0,512) -> xbuf bf16, [512,1024) -> zbuf bf16
__global__ __launch_bounds__(256) void k_gemm_in(
    const u16* __restrict__ A, const u16* __restrict__ Bm,
    u16* __restrict__ xout, u16* __restrict__ zout) {
  __shared__ u16 lA[128 * 32], lB[128 * 32];
  int mt = blockIdx.x, nt = blockIdx.y;
  int t = threadIdx.x, lane = t & 63, wid = t >> 6;
  int wr = wid >> 1, wc = wid & 1;
  f32x4 acc[4][4] = {};
  const u16* Ab = A + (size_t)mt * 128 * 256;
  const u16* Bb = Bm + (size_t)nt * 128 * 256;
  for (int kt = 0; kt < 8; ++kt) {
    int k0 = kt * 32;
    __syncthreads();
#pragma unroll
    for (int i = 0; i < 2; ++i) {
      int lin = i * 256 + t, row = lin >> 2, kc = lin & 3;
      *(short8*)&lA[lin * 8] = *(const short8*)&Ab[row * 256 + k0 + kc * 8];
      *(short8*)&lB[lin * 8] = *(const short8*)&Bb[row * 256 + k0 + kc * 8];
    }
    __syncthreads();
    short8 av[4], bv[4];
#pragma unroll
    for (int i = 0; i < 4; ++i)
      av[i] = *(const short8*)&lA[(wr * 64 + i * 16 + (lane & 15)) * 32 + (lane >> 4) * 8];
#pragma unroll
    for (int j = 0; j < 4; ++j)
      bv[j] = *(const short8*)&lB[(wc * 64 + j * 16 + (lane & 15)) * 32 + (lane >> 4) * 8];
#pragma unroll
    for (int i = 0; i < 4; ++i)
#pragma unroll
      for (int j = 0; j < 4; ++j)
        acc[i][j] = __builtin_amdgcn_mfma_f32_16x16x32_bf16(av[i], bv[j], acc[i][j], 0, 0, 0);
  }
  int colbase = nt * 128 + wc * 64;
  u16* dst = (colbase < 512) ? xout : zout;
  int cadj = (colbase < 512) ? colbase : colbase - 512;
  size_t rowbase = (size_t)mt * 128 + wr * 64;
#pragma unroll
  for (int i = 0; i < 4; ++i)
#pragma unroll
    for (int j = 0; j < 4; ++j) {
      int c = cadj + j * 16 + (lane & 15);
      size_t rr = rowbase + i * 16 + ((lane >> 4) << 2);
#pragma unroll
      for (int ii = 0; ii < 4; ++ii)
        dst[(rr + ii) * 512 + c] = f2bf(acc[i][j][ii]);
    }
}

// ---------------- conv(d,k=4,causal)+SiLU -> bf16 (logical order per dir) --
__global__ __launch_bounds__(512) void k_conv(
    const u16* __restrict__ xbuf,
    const float* __restrict__ cw_f, const float* __restrict__ cb_f,
    const float* __restrict__ cw_b, const float* __restrict__ cb_b,
    u16* __restrict__ xconv_bf) {
  int d = threadIdx.x;
  int b = blockIdx.y, dir = blockIdx.z;
  int t0 = blockIdx.x * 64;
  const float* cw = (dir ? cw_b : cw_f) + d * 4;
  float w0 = cw[0], w1 = cw[1], w2 = cw[2], w3 = cw[3];
  float bias = (dir ? cb_b : cb_f)[d];
  const u16* xb = xbuf + (size_t)b * L_SEQ * 512 + d;
  u16* ob = xconv_bf + ((size_t)dir * BLROWS + (size_t)b * L_SEQ) * 512 + d;
  float tp0 = 0.f, tp1 = 0.f, tp2 = 0.f;
  if (t0 >= 1) tp2 = bf2f(xb[(size_t)(dir ? (L_SEQ - t0) : (t0 - 1)) * 512]);
  if (t0 >= 2) tp1 = bf2f(xb[(size_t)(dir ? (L_SEQ + 1 - t0) : (t0 - 2)) * 512]);
  if (t0 >= 3) tp0 = bf2f(xb[(size_t)(dir ? (L_SEQ + 2 - t0) : (t0 - 3)) * 512]);
#pragma unroll 4
  for (int tt = t0; tt < t0 + 64; ++tt) {
    int px = dir ? (L_SEQ - 1 - tt) : tt;
    float xin = bf2f(xb[(size_t)px * 512]);
    float u = bias + w0 * tp0 + w1 * tp1 + w2 * tp2 + w3 * xin;
    ob[(size_t)tt * 512] = f2bf(silu_(u));
    tp0 = tp1; tp1 = tp2; tp2 = xin;
  }
}

// ---------------- GEMM2: dbl = xconv @ x_proj_w^T (M=32768,N=48,K=512) -----
__global__ __launch_bounds__(256) void k_gemm_xp(
    const u16* __restrict__ xc, const u16* __restrict__ wxp,
    float* __restrict__ dbl) {
  __shared__ u16 lA[128 * 32], lB[48 * 32];
  int mt = blockIdx.x, dir = blockIdx.y;
  int t = threadIdx.x, lane = t & 63, wid = t >> 6;
  const u16* Ab = xc + ((size_t)dir * BLROWS + (size_t)mt * 128) * 512;
  const u16* Bb = wxp + (size_t)dir * 48 * 512;
  float* Ob = dbl + ((size_t)dir * BLROWS + (size_t)mt * 128) * 48;
  f32x4 acc[2][3] = {};
  for (int kt = 0; kt < 16; ++kt) {
    int k0 = kt * 32;
    __syncthreads();
#pragma unroll
    for (int i = 0; i < 2; ++i) {
      int lin = i * 256 + t, row = lin >> 2, kc = lin & 3;
      *(short8*)&lA[lin * 8] = *(const short8*)&Ab[row * 512 + k0 + kc * 8];
    }
    if (t < 192) {
      int row = t >> 2, kc = t & 3;
      *(short8*)&lB[t * 8] = *(const short8*)&Bb[row * 512 + k0 + kc * 8];
    }
    __syncthreads();
    short8 av[2], bv[3];
#pragma unroll
    for (int i = 0; i < 2; ++i)
      av[i] = *(const short8*)&lA[(wid * 32 + i * 16 + (lane & 15)) * 32 + (lane >> 4) * 8];
#pragma unroll
    for (int j = 0; j < 3; ++j)
      bv[j] = *(const short8*)&lB[(j * 16 + (lane & 15)) * 32 + (lane >> 4) * 8];
#pragma unroll
    for (int i = 0; i < 2; ++i)
#pragma unroll
      for (int j = 0; j < 3; ++j)
        acc[i][j] = __builtin_amdgcn_mfma_f32_16x16x32_bf16(av[i], bv[j], acc[i][j], 0, 0, 0);
  }
#pragma unroll
  for (int i = 0; i < 2; ++i)
#pragma unroll
    for (int j = 0; j < 3; ++j) {
      int c = j * 16 + (lane & 15);
      int rr = wid * 32 + i * 16 + ((lane >> 4) << 2);
#pragma unroll
      for (int ii = 0; ii < 4; ++ii)
        Ob[(size_t)(rr + ii) * 48 + c] = acc[i][j][ii];
    }
}

// ---------------- scan phase A: per-chunk aggregates (P, Hf) ---------------
// lane = channel d; conv + dt_proj + softplus recomputed inline.
// ALL per-thread state in f32x4 regs with compile-time indices (no allocas).
__global__ __launch_bounds__(512, 4) void k_scanA(
    const u16* __restrict__ xbuf, const float* __restrict__ dbl,
    const float* __restrict__ a2buf,
    const float* __restrict__ cw_f, const float* __restrict__ cb_f,
    const float* __restrict__ cw_b, const float* __restrict__ cb_b,
    const float* __restrict__ dtw_f, const float* __restrict__ dtb_f,
    const float* __restrict__ dtw_b, const float* __restrict__ dtb_b,
    float* __restrict__ Pb, float* __restrict__ Hf) {
  int chunk = blockIdx.x, b = blockIdx.y, dir = blockIdx.z;
  int d = threadIdx.x;
  f32x4 a2r[4], w3r[4];
  const f32x4* A2 = (const f32x4*)(a2buf + dir * 8192 + (size_t)d * 16);
  const f32x4* dtw = (const f32x4*)((dir ? dtw_b : dtw_f) + (size_t)d * 16);
#pragma unroll
  for (int q = 0; q < 4; ++q) { a2r[q] = A2[q]; w3r[q] = dtw[q]; }
  const float* cw = (dir ? cw_b : cw_f) + d * 4;
  float w0 = cw[0], w1 = cw[1], w2 = cw[2], w3 = cw[3];
  float cbias = (dir ? cb_b : cb_f)[d];
  float dtbias = (dir ? dtb_b : dtb_f)[d];
  const u16* xb = xbuf + (size_t)b * L_SEQ * 512 + d;
  const float* dbr = dbl + ((size_t)dir * BLROWS + (size_t)b * L_SEQ) * 48;
  int t0 = chunk * CLEN;
  float tp0 = 0.f, tp1 = 0.f, tp2 = 0.f;
  if (t0 >= 1) tp2 = bf2f(xb[(size_t)(dir ? (L_SEQ - t0) : (t0 - 1)) * 512]);
  if (t0 >= 2) tp1 = bf2f(xb[(size_t)(dir ? (L_SEQ + 1 - t0) : (t0 - 2)) * 512]);
  if (t0 >= 3) tp0 = bf2f(xb[(size_t)(dir ? (L_SEQ + 2 - t0) : (t0 - 3)) * 512]);
  f32x4 h[4] = {};
  float S = 0.f;
  for (int tt = t0; tt < t0 + CLEN; ++tt) {
    int px = dir ? (L_SEQ - 1 - tt) : tt;
    float xin = bf2f(xb[(size_t)px * 512]);
    float u = silu_(cbias + w0 * tp0 + w1 * tp1 + w2 * tp2 + w3 * xin);
    tp0 = tp1; tp1 = tp2; tp2 = xin;
    const f32x4* row4 = (const f32x4*)(dbr + (size_t)tt * 48);
    float v0 = 0.f, v1 = 0.f, v2 = 0.f, v3 = 0.f;
#pragma unroll
    for (int q = 0; q < 4; ++q) {
      f32x4 dq = row4[q];
      v0 = fmaf(dq[0], w3r[q][0], v0); v1 = fmaf(dq[1], w3r[q][1], v1);
      v2 = fmaf(dq[2], w3r[q][2], v2); v3 = fmaf(dq[3], w3r[q][3], v3);
    }
    float delta = softplus_(dtbias + ((v0 + v1) + (v2 + v3)));
    S += delta;
    float du = delta * u;
#pragma unroll
    for (int q = 0; q < 4; ++q) {
      f32x4 Bv = row4[4 + q];
#pragma unroll
      for (int j = 0; j < 4; ++j)
        h[q][j] = fmaf(exp2fast(delta * a2r[q][j]), h[q][j], du * Bv[j]);
    }
  }
  size_t base = (((size_t)dir * NBATCH + b) * NC_CHUNKS + chunk) * 8192 + (size_t)d * 16;
#pragma unroll
  for (int q = 0; q < 4; ++q) {
    *(f32x4*)&Hf[base + q * 4] = h[q];
    f32x4 pv;
#pragma unroll
    for (int j = 0; j < 4; ++j) pv[j] = exp2fast(S * a2r[q][j]);
    *(f32x4*)&Pb[base + q * 4] = pv;
  }
}

// ---------------- scan phase B: compose chunk aggregates -> Hinit ----------
__global__ __launch_bounds__(512) void k_scanB(
    const float* __restrict__ P, const float* __restrict__ Hf,
    float* __restrict__ Hi) {
  int dir = blockIdx.z, b = blockIdx.y;
  int j = blockIdx.x * 512 + threadIdx.x;   // 0..8191
  size_t base0 = (((size_t)dir * NBATCH + b) * NC_CHUNKS) * 8192 + j;
  float h = 0.f;
  for (int c = 0; c < NC_CHUNKS; ++c) {
    size_t idx = base0 + (size_t)c * 8192;
    Hi[idx] = h;
    h = P[idx] * h + Hf[idx];
  }
}

// ---------------- scan phase C: full scan + D*u + silu(z) gate -> ycat -----
__global__ __launch_bounds__(512, 4) void k_scanC(
    const u16* __restrict__ xbuf, const u16* __restrict__ zbuf,
    const float* __restrict__ dbl, const float* __restrict__ a2buf,
    const float* __restrict__ cw_f, const float* __restrict__ cb_f,
    const float* __restrict__ cw_b, const float* __restrict__ cb_b,
    const float* __restrict__ dtw_f, const float* __restrict__ dtb_f,
    const float* __restrict__ dtw_b, const float* __restrict__ dtb_b,
    const float* __restrict__ D_f, const float* __restrict__ D_b,
    const float* __restrict__ Hi, u16* __restrict__ ycat) {
  int chunk = blockIdx.x, b = blockIdx.y, dir = blockIdx.z;
  int d = threadIdx.x;
  f32x4 a2r[4], w3r[4];
  const f32x4* A2 = (const f32x4*)(a2buf + dir * 8192 + (size_t)d * 16);
  const f32x4* dtw = (const f32x4*)((dir ? dtw_b : dtw_f) + (size_t)d * 16);
#pragma unroll
  for (int q = 0; q < 4; ++q) { a2r[q] = A2[q]; w3r[q] = dtw[q]; }
  const float* cw = (dir ? cw_b : cw_f) + d * 4;
  float w0 = cw[0], w1 = cw[1], w2 = cw[2], w3 = cw[3];
  float cbias = (dir ? cb_b : cb_f)[d];
  float dtbias = (dir ? dtb_b : dtb_f)[d];
  float Dd = (dir ? D_b : D_f)[d];
  const u16* xb = xbuf + (size_t)b * L_SEQ * 512 + d;
  const u16* zb = zbuf + (size_t)b * L_SEQ * 512 + d;
  const float* dbr = dbl + ((size_t)dir * BLROWS + (size_t)b * L_SEQ) * 48;
  u16* yb = ycat + (size_t)b * L_SEQ * 1024 + dir * 512 + d;
  int t0 = chunk * CLEN;
  float tp0 = 0.f, tp1 = 0.f, tp2 = 0.f;
  if (t0 >= 1) tp2 = bf2f(xb[(size_t)(dir ? (L_SEQ - t0) : (t0 - 1)) * 512]);
  if (t0 >= 2) tp1 = bf2f(xb[(size_t)(dir ? (L_SEQ + 1 - t0) : (t0 - 2)) * 512]);
  if (t0 >= 3) tp0 = bf2f(xb[(size_t)(dir ? (L_SEQ + 2 - t0) : (t0 - 3)) * 512]);
  f32x4 h[4];
  size_t hbase = (((size_t)dir * NBATCH + b) * NC_CHUNKS + chunk) * 8192 + (size_t)d * 16;
#pragma unroll
  for (int q = 0; q < 4; ++q) h[q] = *(const f32x4*)&Hi[hbase + q * 4];
  for (int tt = t0; tt < t0 + CLEN; ++tt) {
    int px = dir ? (L_SEQ - 1 - tt) : tt;
    float xin = bf2f(xb[(size_t)px * 512]);
    float u = silu_(cbias + w0 * tp0 + w1 * tp1 + w2 * tp2 + w3 * xin);
    tp0 = tp1; tp1 = tp2; tp2 = xin;
    const f32x4* row4 = (const f32x4*)(dbr + (size_t)tt * 48);
    float v0 = 0.f, v1 = 0.f, v2 = 0.f, v3 = 0.f;
#pragma unroll
    for (int q = 0; q < 4; ++q) {
      f32x4 dq = row4[q];
      v0 = fmaf(dq[0], w3r[q][0], v0); v1 = fmaf(dq[1], w3r[q][1], v1);
      v2 = fmaf(dq[2], w3r[q][2], v2); v3 = fmaf(dq[3], w3r[q][3], v3);
    }
    float delta = softplus_(dtbias + ((v0 + v1) + (v2 + v3)));
    float du = delta * u;
    f32x4 yv = {0.f, 0.f, 0.f, 0.f};
#pragma unroll
    for (int q = 0; q < 4; ++q) {
      f32x4 Bv = row4[4 + q];
      f32x4 Cv = row4[8 + q];
#pragma unroll
      for (int j = 0; j < 4; ++j) {
        h[q][j] = fmaf(exp2fast(delta * a2r[q][j]), h[q][j], du * Bv[j]);
        yv[j] = fmaf(h[q][j], Cv[j], yv[j]);
      }
    }
    float y = ((yv[0] + yv[1]) + (yv[2] + yv[3])) + u * Dd;
    float z = bf2f(zb[(size_t)px * 512]);
    yb[(size_t)px * 1024] = f2bf(y * silu_(z));
  }
}

// ---------------- GEMM3: out = ycat @ [W|W]^T (M=32768,N=256,K=1024) -------
// epilogue writes transposed: out[b][c][l]
__global__ __launch_bounds__(256) void k_gemm_out(
    const u16* __restrict__ A, const u16* __restrict__ Bm,
    float* __restrict__ out) {
  __shared__ u16 lA[128 * 32], lB[128 * 32];
  int mt = blockIdx.x, nt = blockIdx.y;
  int t = threadIdx.x, lane = t & 63, wid = t >> 6;
  int wr = wid >> 1, wc = wid & 1;
  f32x4 acc[4][4] = {};
  const u16* Ab = A + (size_t)mt * 128 * 1024;
  const u16* Bb = Bm + (size_t)nt * 128 * 1024;
  for (int kt = 0; kt < 32; ++kt) {
    int k0 = kt * 32;
    __syncthreads();
#pragma unroll
    for (int i = 0; i < 2; ++i) {
      int lin = i * 256 + t, row = lin >> 2, kc = lin & 3;
      *(short8*)&lA[lin * 8] = *(const short8*)&Ab[(size_t)row * 1024 + k0 + kc * 8];
      *(short8*)&lB[lin * 8] = *(const short8*)&Bb[(size_t)row * 1024 + k0 + kc * 8];
    }
    __syncthreads();
    short8 av[4], bv[4];
#pragma unroll
    for (int i = 0; i < 4; ++i)
      av[i] = *(const short8*)&lA[(wr * 64 + i * 16 + (lane & 15)) * 32 + (lane >> 4) * 8];
#pragma unroll
    for (int j = 0; j < 4; ++j)
      bv[j] = *(const short8*)&lB[(wc * 64 + j * 16 + (lane & 15)) * 32 + (lane >> 4) * 8];
#pragma unroll
    for (int i = 0; i < 4; ++i)
#pragma unroll
      for (int j = 0; j < 4; ++j)
        acc[i][j] = __builtin_amdgcn_mfma_f32_16x16x32_bf16(av[i], bv[j], acc[i][j], 0, 0, 0);
  }
#pragma unroll
  for (int i = 0; i < 4; ++i)
#pragma unroll
    for (int j = 0; j < 4; ++j) {
      int c = nt * 128 + wc * 64 + j * 16 + (lane & 15);
      int r0 = mt * 128 + wr * 64 + i * 16 + ((lane >> 4) << 2);
      int b = r0 >> 12, l0 = r0 & 4095;
      float4 val;
      val.x = acc[i][j][0]; val.y = acc[i][j][1];
      val.z = acc[i][j][2]; val.w = acc[i][j][3];
      *(float4*)&out[((size_t)b * 256 + c) * 4096 + l0] = val;
    }
}

// ---------------- host launcher --------------------------------------------
extern "C" void kernel_launch(void* const* d_in, const int* in_sizes, int n_in,
                              void* d_out, int out_size, void* d_ws, size_t ws_size,
                              hipStream_t stream) {
  (void)in_sizes; (void)n_in; (void)out_size; (void)ws_size;
  const float* x      = (const float*)d_in[0];
  const float* ln_w   = (const float*)d_in[1];
  const float* ln_b   = (const float*)d_in[2];
  const float* in_w   = (const float*)d_in[3];
  const float* cw_f   = (const float*)d_in[4];
  const float* cb_f   = (const float*)d_in[5];
  const float* xp_f   = (const float*)d_in[6];
  const float* dtw_f  = (const float*)d_in[7];
  const float* dtb_f  = (const float*)d_in[8];
  const float* Alog_f = (const float*)d_in[9];
  const float* D_f    = (const float*)d_in[10];
  const float* cw_b   = (const float*)d_in[11];
  const float* cb_b   = (const float*)d_in[12];
  const float* xp_b   = (const float*)d_in[13];
  const float* dtw_b  = (const float*)d_in[14];
  const float* dtb_b  = (const float*)d_in[15];
  const float* Alog_b = (const float*)d_in[16];
  const float* D_b    = (const float*)d_in[17];
  const float* out_w  = (const float*)d_in[18];

  char* ws = (char*)d_ws;
  size_t off = 0;
  auto alloc = [&](size_t bytes) -> void* {
    void* p = ws + off;
    off += (bytes + 255) & ~(size_t)255;
    return p;
  };
  // Lifetime-aliased workspace layout (peak ~198 MB):
  //  xn_bf [k_ln -> k_gemm_in]  aliases  Pbuf [k_scanA -> k_scanB]  (both 16.78 MB)
  //  xconv [k_conv -> k_gemm_xp] aliases ycat [k_scanC -> k_gemm_out] (both 67 MB)
  u16*   xn_bf  = (u16*)  alloc((size_t)BLROWS * 256 * 2);        // 16.78 MB (== Pbuf)
  u16*   wb_in  = (u16*)  alloc((size_t)1024 * 256 * 2);
  u16*   wb_xp  = (u16*)  alloc((size_t)2 * 48 * 512 * 2);
  u16*   wb_cat = (u16*)  alloc((size_t)256 * 1024 * 2);
  float* a2buf  = (float*)alloc((size_t)2 * 8192 * 4);
  u16*   xbuf   = (u16*)  alloc((size_t)BLROWS * 512 * 2);        // 33.5 MB bf16
  u16*   zbuf   = (u16*)  alloc((size_t)BLROWS * 512 * 2);        // 33.5 MB bf16
  u16*   xconv  = (u16*)  alloc((size_t)2 * BLROWS * 512 * 2);    // 67 MB (== ycat)
  float* dblb   = (float*)alloc((size_t)2 * BLROWS * 48 * 4);     // 12.6 MB
  float* Hfbuf  = (float*)alloc((size_t)2 * NBATCH * NC_CHUNKS * 8192 * 4);  // 16.78 MB
  float* Hibuf  = (float*)alloc((size_t)2 * NBATCH * NC_CHUNKS * 8192 * 4);  // 16.78 MB
  float* Pbuf   = (float*)xn_bf;   // alias: xn_bf dead after k_gemm_in
  u16*   ycat   = xconv;           // alias: xconv dead after k_gemm_xp

  hipLaunchKernelGGL(k_prep, dim3(1024), dim3(256), 0, stream,
                     in_w, xp_f, xp_b, out_w, Alog_f, Alog_b,
                     wb_in, wb_xp, wb_cat, a2buf);
  hipLaunchKernelGGL(k_ln, dim3(L_SEQ / 64, NBATCH), dim3(256), 0, stream,
                     x, ln_w, ln_b, xn_bf);
  hipLaunchKernelGGL(k_gemm_in, dim3(BLROWS / 128, 8), dim3(256), 0, stream,
                     xn_bf, wb_in, xbuf, zbuf);
  hipLaunchKernelGGL(k_conv, dim3(L_SEQ / 64, NBATCH, 2), dim3(512), 0, stream,
                     xbuf, cw_f, cb_f, cw_b, cb_b, xconv);
  hipLaunchKernelGGL(k_gemm_xp, dim3(BLROWS / 128, 2), dim3(256), 0, stream,
                     xconv, wb_xp, dblb);
  hipLaunchKernelGGL(k_scanA, dim3(NC_CHUNKS, NBATCH, 2), dim3(512), 0, stream,
                     xbuf, dblb, a2buf, cw_f, cb_f, cw_b, cb_b,
                     dtw_f, dtb_f, dtw_b, dtb_b, Pbuf, Hfbuf);
  hipLaunchKernelGGL(k_scanB, dim3(16, NBATCH, 2), dim3(512), 0, stream,
                     Pbuf, Hfbuf, Hibuf);
  hipLaunchKernelGGL(k_scanC, dim3(NC_CHUNKS, NBATCH, 2), dim3(512), 0, stream,
                     xbuf, zbuf, dblb, a2buf, cw_f, cb_f, cw_b, cb_b,
                     dtw_f, dtb_f, dtw_b, dtb_b, D_f, D_b, Hibuf, ycat);
  hipLaunchKernelGGL(k_gemm_out, dim3(BLROWS / 128, 2), dim3(256), 0, stream,
                     ycat, wb_cat, (float*)d_out);
}